// Round 9
// baseline (794.204 us; speedup 1.0000x reference)
//
#include <hip/hip_runtime.h>
#include <math.h>

// Problem constants
#define BB 16
#define CHN 256
#define TT 576
#define NHD 8
#define DHD 32
#define SCALE_F 0.17677669529663687f  // 1/sqrt(32)

// XOR chunk swizzle: element (row p, depth d) -> byte-conflict-free float offset
__device__ __forceinline__ int SW(int p, int d) {
    return ((((d >> 2) ^ (p & 7)) << 2) | (d & 3));
}

// ---------------------------------------------------------------------------
// Kernel A: QKV 1x1-conv GEMM.  out[b][o][i] = sum_c w[o][c]*x[b][c][i] + bias[o]
// Grid: 16 b * 16 i-tiles(36) * 3 o-chunks(256) = 768 blocks, 256 threads.
// ---------------------------------------------------------------------------
__global__ __launch_bounds__(256) void qkv_gemm_k(const float* __restrict__ x,
                                                  const float* __restrict__ w,
                                                  const float* __restrict__ bias,
                                                  float* __restrict__ out) {
    __shared__ float ws[32 * 260];   // [kc][oo], stride 260
    __shared__ float xs[32 * 36];    // [kc][ii]
    int orig = blockIdx.x;
    int wg = (orig & 7) * 96 + (orig >> 3);      // XCD-chunked swizzle
    int b = wg / 48;
    int rem = wg % 48;
    int it = rem / 3, oh = rem % 3;
    int o0 = oh * 256, i0 = it * 36;
    int tid = threadIdx.x;
    int og = tid >> 2, itg = tid & 3;            // thread owns 4 o x 9 i

    float acc[4][9];
#pragma unroll
    for (int r = 0; r < 4; ++r)
#pragma unroll
        for (int s = 0; s < 9; ++s) acc[r][s] = 0.f;

    for (int kt = 0; kt < 8; ++kt) {
        for (int idx4 = tid; idx4 < 2048; idx4 += 256) {
            int oo = idx4 >> 3, kc4 = (idx4 & 7) * 4;
            const float4 v = *reinterpret_cast<const float4*>(&w[(o0 + oo) * 256 + kt * 32 + kc4]);
            ws[(kc4 + 0) * 260 + oo] = v.x;
            ws[(kc4 + 1) * 260 + oo] = v.y;
            ws[(kc4 + 2) * 260 + oo] = v.z;
            ws[(kc4 + 3) * 260 + oo] = v.w;
        }
        for (int idx4 = tid; idx4 < 288; idx4 += 256) {
            int kc = idx4 / 9, ii4 = idx4 % 9;
            const float4 v = *reinterpret_cast<const float4*>(&x[(b * 256 + kt * 32 + kc) * 576 + i0 + ii4 * 4]);
            *reinterpret_cast<float4*>(&xs[kc * 36 + ii4 * 4]) = v;
        }
        __syncthreads();
#pragma unroll 8
        for (int kc = 0; kc < 32; ++kc) {
            float4 wr = *reinterpret_cast<const float4*>(&ws[kc * 260 + og * 4]);
            float xv[9];
#pragma unroll
            for (int s = 0; s < 9; ++s) xv[s] = xs[kc * 36 + itg * 9 + s];
#pragma unroll
            for (int s = 0; s < 9; ++s) {
                acc[0][s] += wr.x * xv[s];
                acc[1][s] += wr.y * xv[s];
                acc[2][s] += wr.z * xv[s];
                acc[3][s] += wr.w * xv[s];
            }
        }
        __syncthreads();
    }
#pragma unroll
    for (int r = 0; r < 4; ++r) {
        int o = o0 + og * 4 + r;
        float bb = bias[o];
#pragma unroll
        for (int s = 0; s < 9; ++s)
            out[(b * 768 + o) * 576 + i0 + itg * 9 + s] = acc[r][s] + bb;
    }
}

// ---------------------------------------------------------------------------
// Kernel C: fused relative-position attention — 512-thread version.
// Grid: 256 blocks (16 b x 16 i-tiles of 36), 8 waves/block (2/SIMD), 123 KB LDS.
// __launch_bounds__(512) WITHOUT a min-waves arg: the 8-wave block already
// guarantees 2 waves/SIMD at <=256 VGPR; the old ",2" wrongly capped the
// allocator at 128 VGPR and forced a ~1 GB/dispatch scratch spill.
// ---------------------------------------------------------------------------
__global__ __launch_bounds__(512) void attn_k(const float* __restrict__ qkv,
                                              const float* __restrict__ rh_k,
                                              const float* __restrict__ rw_k,
                                              const float* __restrict__ rh_v,
                                              const float* __restrict__ rw_v,
                                              float* __restrict__ att_out) {
    __shared__ float qs[12288];   // q [n][iw=48][d=32] swizzled; epilogue: (rh_v+rw_v) stride 260
    __shared__ float kvs[12288];  // in-loop: K @0, V @6144, [n][c=24][d] swizzled; pre-loop: (rh_k+rw_k) stride 260
    __shared__ float ats[6912];   // logits/probs [n][i=36][c=24]; end: colsum

    int orig = blockIdx.x;
    int wg = (orig & 7) * 32 + (orig >> 3);      // XCD-chunked swizzle (256 % 8 == 0)
    int b = wg >> 4, it = wg & 15;
    int i0 = it * 36;
    int tid = threadIdx.x;
    const float* qb = qkv + (size_t)b * 768 * 576;

    // thread ids
    int n1 = tid >> 6;                 // wave == head
    int lane = tid & 63;
    int slot = lane & 31, dh = lane >> 5;          // phase1: d-half split
    int ig1 = slot >> 3, jg1 = slot & 7;           // phase1: 9 i x 3 c
    int dg = lane >> 3;                            // phase2: 8 d-groups
    int ig2 = (lane >> 1) & 3, ch = lane & 1;      // phase2: 4 i-groups x 2 c-halves
    int d0 = dg * 4, ib = ig2 * 9;

    // ---- load q window rows [i0, i0+48) (clipped) transposed into qs ----
    for (int idx4 = tid; idx4 < 3072; idx4 += 512) {
        int o = idx4 / 12, iw4 = (idx4 % 12) * 4;
        int n = o >> 5, d = o & 31;
        int gi = i0 + iw4;
        float4 v;
        if (gi + 3 < 576) {
            v = *reinterpret_cast<const float4*>(&qb[o * 576 + gi]);
        } else {
            v.x = (gi + 0 < 576) ? qb[o * 576 + gi + 0] : 0.f;
            v.y = (gi + 1 < 576) ? qb[o * 576 + gi + 1] : 0.f;
            v.z = (gi + 2 < 576) ? qb[o * 576 + gi + 2] : 0.f;
            v.w = (gi + 3 < 576) ? qb[o * 576 + gi + 3] : 0.f;
        }
        qs[n * 1536 + (iw4 + 0) * 32 + SW(iw4 + 0, d)] = v.x;
        qs[n * 1536 + (iw4 + 1) * 32 + SW(iw4 + 1, d)] = v.y;
        qs[n * 1536 + (iw4 + 2) * 32 + SW(iw4 + 2, d)] = v.z;
        qs[n * 1536 + (iw4 + 3) * 32 + SW(iw4 + 3, d)] = v.w;
    }
    // ---- load rh_k + rw_k into kvs (stride 260) ----
    for (int idx = tid; idx < 12032; idx += 512) {
        int j = idx >> 8, nd = idx & 255;
        kvs[j * 260 + nd] = rh_k[idx] + rw_k[idx];
    }

    // ---- prefetch K/V tile tt=0 into registers ----
    float4 kvf[3], vvf[3];
    {
        const float* kb = qb + 256 * 576;
        const float* vb = qb + 512 * 576;
#pragma unroll
        for (int k = 0; k < 3; ++k) {
            int idx4 = tid + k * 512;
            int o = idx4 / 6, c4 = (idx4 % 6) * 4;
            kvf[k] = *reinterpret_cast<const float4*>(&kb[o * 576 + c4]);
            vvf[k] = *reinterpret_cast<const float4*>(&vb[o * 576 + c4]);
        }
    }
    __syncthreads();

    // ---- bd HALF-dots into registers: bdreg[r][s] = dot16(q[:,isrc], table[j-1]) ----
    float bdreg[9][3];
#pragma unroll
    for (int r = 0; r < 9; ++r) {
        int i_loc = ig1 * 9 + r;
        int f0 = 576 + 47 * (i0 + i_loc);
#pragma unroll
        for (int s = 0; s < 3; ++s) {
            int c = jg1 * 3 + s;
            int f = f0 + c;
            int j = f % 48;
            float val = 0.f;
            if (j > 0) {
                int isl = f / 48 - i0;   // proven in [0,48)
                int bq = n1 * 1536 + isl * 32;
                int swz = isl & 7;
                int br = (j - 1) * 260 + n1 * 32 + dh * 16;
#pragma unroll
                for (int dq = 0; dq < 4; ++dq) {
                    int dqq = dh * 4 + dq;
                    float4 qv = *reinterpret_cast<const float4*>(&qs[bq + ((dqq ^ swz) << 2)]);
                    float4 rv = *reinterpret_cast<const float4*>(&kvs[br + dq * 4]);
                    val += qv.x * rv.x + qv.y * rv.y + qv.z * rv.z + qv.w * rv.w;
                }
            }
            bdreg[r][s] = val;
        }
    }

    // persistent per-thread state
    float cs[2][8];      // colsum for softmax-owned (i,c) pairs
#pragma unroll
    for (int k = 0; k < 2; ++k)
#pragma unroll
        for (int nn = 0; nn < 8; ++nn) cs[k][nn] = 0.f;
    float acc[4][9];     // output partials: (d0..d0+3) x (ib..ib+8), c-half ch
#pragma unroll
    for (int r = 0; r < 4; ++r)
#pragma unroll
        for (int s = 0; s < 9; ++s) acc[r][s] = 0.f;

    for (int tt = 0; tt < 24; ++tt) {
        __syncthreads();   // barA: prev phase2 done (kvs/table free)
        // ---- write staged K/V regs into LDS [n][c][d] swizzled ----
#pragma unroll
        for (int k = 0; k < 3; ++k) {
            int idx4 = tid + k * 512;
            int o = idx4 / 6, c4 = (idx4 % 6) * 4;
            int n = o >> 5, d = o & 31;
            int base = n * 768;
            kvs[base + (c4 + 0) * 32 + SW(c4 + 0, d)] = kvf[k].x;
            kvs[base + (c4 + 1) * 32 + SW(c4 + 1, d)] = kvf[k].y;
            kvs[base + (c4 + 2) * 32 + SW(c4 + 2, d)] = kvf[k].z;
            kvs[base + (c4 + 3) * 32 + SW(c4 + 3, d)] = kvf[k].w;
            kvs[6144 + base + (c4 + 0) * 32 + SW(c4 + 0, d)] = vvf[k].x;
            kvs[6144 + base + (c4 + 1) * 32 + SW(c4 + 1, d)] = vvf[k].y;
            kvs[6144 + base + (c4 + 2) * 32 + SW(c4 + 2, d)] = vvf[k].z;
            kvs[6144 + base + (c4 + 3) * 32 + SW(c4 + 3, d)] = vvf[k].w;
        }
        // ---- prefetch next tile into regs (hidden under phase1/2) ----
        if (tt + 1 < 24) {
            const float* kb = qb + 256 * 576 + (tt + 1) * 24;
            const float* vb = qb + 512 * 576 + (tt + 1) * 24;
#pragma unroll
            for (int k = 0; k < 3; ++k) {
                int idx4 = tid + k * 512;
                int o = idx4 / 6, c4 = (idx4 % 6) * 4;
                kvf[k] = *reinterpret_cast<const float4*>(&kb[o * 576 + c4]);
                vvf[k] = *reinterpret_cast<const float4*>(&vb[o * 576 + c4]);
            }
        }
        __syncthreads();   // barB: K/V tile ready

        // ---- phase 1: half-logits (qk_half + bd_half), shfl-combine, write ----
        {
            float a[9][3];
#pragma unroll
            for (int r = 0; r < 9; ++r)
#pragma unroll
                for (int s = 0; s < 3; ++s) a[r][s] = bdreg[r][s];
#pragma unroll
            for (int dq = 0; dq < 4; ++dq) {
                int dqq = dh * 4 + dq;
                float4 qv[9], kv[3];
#pragma unroll
                for (int r = 0; r < 9; ++r) {
                    int iw = ig1 * 9 + r;
                    qv[r] = *reinterpret_cast<const float4*>(&qs[n1 * 1536 + iw * 32 + ((dqq ^ (iw & 7)) << 2)]);
                }
#pragma unroll
                for (int s = 0; s < 3; ++s) {
                    int c = jg1 * 3 + s;
                    kv[s] = *reinterpret_cast<const float4*>(&kvs[n1 * 768 + c * 32 + ((dqq ^ (c & 7)) << 2)]);
                }
#pragma unroll
                for (int r = 0; r < 9; ++r)
#pragma unroll
                    for (int s = 0; s < 3; ++s)
                        a[r][s] += qv[r].x * kv[s].x + qv[r].y * kv[s].y +
                                   qv[r].z * kv[s].z + qv[r].w * kv[s].w;
            }
#pragma unroll
            for (int r = 0; r < 9; ++r)
#pragma unroll
                for (int s = 0; s < 3; ++s)
                    a[r][s] += __shfl_xor(a[r][s], 32);   // combine d-halves
            if (dh == 0) {
#pragma unroll
                for (int r = 0; r < 9; ++r)
#pragma unroll
                    for (int s = 0; s < 3; ++s)
                        ats[n1 * 864 + (ig1 * 9 + r) * 24 + jg1 * 3 + s] = a[r][s] * SCALE_F;
            }
        }
        __syncthreads();   // barC: logits ready

        // ---- softmax over 8 heads per (i,c); colsum in regs ----
        {
            int p = tid;
            float xv[8];
#pragma unroll
            for (int nn = 0; nn < 8; ++nn) xv[nn] = ats[nn * 864 + p];
            float m = xv[0];
#pragma unroll
            for (int nn = 1; nn < 8; ++nn) m = fmaxf(m, xv[nn]);
            float ssum = 0.f;
#pragma unroll
            for (int nn = 0; nn < 8; ++nn) { xv[nn] = __expf(xv[nn] - m); ssum += xv[nn]; }
            float inv = 1.0f / ssum;
#pragma unroll
            for (int nn = 0; nn < 8; ++nn) {
                float aa = xv[nn] * inv;
                ats[nn * 864 + p] = aa;
                cs[0][nn] += aa;
            }
            if (tid < 352) {
                int p2 = 512 + tid;
                float yv[8];
#pragma unroll
                for (int nn = 0; nn < 8; ++nn) yv[nn] = ats[nn * 864 + p2];
                float m2 = yv[0];
#pragma unroll
                for (int nn = 1; nn < 8; ++nn) m2 = fmaxf(m2, yv[nn]);
                float ss2 = 0.f;
#pragma unroll
                for (int nn = 0; nn < 8; ++nn) { yv[nn] = __expf(yv[nn] - m2); ss2 += yv[nn]; }
                float inv2 = 1.0f / ss2;
#pragma unroll
                for (int nn = 0; nn < 8; ++nn) {
                    float aa = yv[nn] * inv2;
                    ats[nn * 864 + p2] = aa;
                    cs[1][nn] += aa;
                }
            }
        }
        __syncthreads();   // barD: probs ready

        // ---- phase 2: acc += attn @ V over this thread's c-half ----
#pragma unroll
        for (int ccq = 0; ccq < 3; ++ccq) {
            int ccbase = ch * 12 + ccq * 4;
            float4 vv[4];
#pragma unroll
            for (int j = 0; j < 4; ++j) {
                int c2 = ccbase + j;
                vv[j] = *reinterpret_cast<const float4*>(&kvs[6144 + n1 * 768 + c2 * 32 + ((dg ^ (c2 & 7)) << 2)]);
            }
#pragma unroll
            for (int s = 0; s < 9; ++s) {
                float4 pv = *reinterpret_cast<const float4*>(&ats[n1 * 864 + (ib + s) * 24 + ccbase]);
                acc[0][s] += vv[0].x * pv.x + vv[1].x * pv.y + vv[2].x * pv.z + vv[3].x * pv.w;
                acc[1][s] += vv[0].y * pv.x + vv[1].y * pv.y + vv[2].y * pv.z + vv[3].y * pv.w;
                acc[2][s] += vv[0].z * pv.x + vv[1].z * pv.y + vv[2].z * pv.z + vv[3].z * pv.w;
                acc[3][s] += vv[0].w * pv.x + vv[1].w * pv.y + vv[2].w * pv.z + vv[3].w * pv.w;
            }
        }
    }
    __syncthreads();   // all phase2 reads of ats done

    // ---- combine c-halves of acc (lane^1 partner) ----
#pragma unroll
    for (int r = 0; r < 4; ++r)
#pragma unroll
        for (int s = 0; s < 9; ++s)
            acc[r][s] += __shfl_xor(acc[r][s], 1);

    // ---- colsum -> ats; (rh_v+rw_v) -> qs (stride 260) ----
    {
        int p = tid;
#pragma unroll
        for (int nn = 0; nn < 8; ++nn) ats[nn * 864 + p] = cs[0][nn];
        if (tid < 352) {
            int p2 = 512 + tid;
#pragma unroll
            for (int nn = 0; nn < 8; ++nn) ats[nn * 864 + p2] = cs[1][nn];
        }
    }
    for (int idx = tid; idx < 12032; idx += 512) {
        int j = idx >> 8, nd = idx & 255;
        qs[j * 260 + nd] = rh_v[idx] + rw_v[idx];
    }
    __syncthreads();

    // ---- positional-value epilogue + write, s-range split by ch.
    //      STATIC unroll over s (acc indices compile-time); runtime guard only.
#pragma unroll
    for (int s = 0; s < 9; ++s) {
        bool mine = (s < 5) ? (ch == 0) : (ch == 1);
        if (mine) {
            int i_loc = ib + s;
            int f0 = 576 + 47 * (i0 + i_loc);
            float a0 = acc[0][s], a1 = acc[1][s], a2 = acc[2][s], a3 = acc[3][s];
#pragma unroll 4
            for (int c = 0; c < 24; ++c) {
                int f = f0 + c;
                int j = f % 48;
                if (j > 0) {
                    float wv = ats[n1 * 864 + i_loc * 24 + c];
                    float4 rr = *reinterpret_cast<const float4*>(&qs[(j - 1) * 260 + n1 * 32 + d0]);
                    a0 += wv * rr.x;
                    a1 += wv * rr.y;
                    a2 += wv * rr.z;
                    a3 += wv * rr.w;
                }
            }
            size_t ob = ((size_t)b * 256 + n1 * 32 + d0) * 576 + i0 + i_loc;
            att_out[ob] = a0;
            att_out[ob + 576] = a1;
            att_out[ob + 1152] = a2;
            att_out[ob + 1728] = a3;
        }
    }
}

// ---------------------------------------------------------------------------
// Kernel D: FC 1x1-conv GEMM + bias + residual. Writes into d_out.
// ---------------------------------------------------------------------------
__global__ __launch_bounds__(256) void fc_k(const float* __restrict__ att,
                                            const float* __restrict__ w,
                                            const float* __restrict__ bias,
                                            const float* __restrict__ x,
                                            float* __restrict__ y) {
    __shared__ float ws[32 * 260];
    __shared__ float as[32 * 36];
    int orig = blockIdx.x;
    int wg = (orig & 7) * 32 + (orig >> 3);
    int b = wg >> 4, it = wg & 15;
    int i0 = it * 36;
    int tid = threadIdx.x;
    int og = tid >> 2, itg = tid & 3;

    float acc[4][9];
#pragma unroll
    for (int r = 0; r < 4; ++r)
#pragma unroll
        for (int s = 0; s < 9; ++s) acc[r][s] = 0.f;

    for (int kt = 0; kt < 8; ++kt) {
        for (int idx4 = tid; idx4 < 2048; idx4 += 256) {
            int oo = idx4 >> 3, kc4 = (idx4 & 7) * 4;
            const float4 v = *reinterpret_cast<const float4*>(&w[oo * 256 + kt * 32 + kc4]);
            ws[(kc4 + 0) * 260 + oo] = v.x;
            ws[(kc4 + 1) * 260 + oo] = v.y;
            ws[(kc4 + 2) * 260 + oo] = v.z;
            ws[(kc4 + 3) * 260 + oo] = v.w;
        }
        for (int idx4 = tid; idx4 < 288; idx4 += 256) {
            int kc = idx4 / 9, ii4 = idx4 % 9;
            const float4 v = *reinterpret_cast<const float4*>(&att[(b * 256 + kt * 32 + kc) * 576 + i0 + ii4 * 4]);
            *reinterpret_cast<float4*>(&as[kc * 36 + ii4 * 4]) = v;
        }
        __syncthreads();
#pragma unroll 8
        for (int kc = 0; kc < 32; ++kc) {
            float4 wr = *reinterpret_cast<const float4*>(&ws[kc * 260 + og * 4]);
            float xv[9];
#pragma unroll
            for (int s = 0; s < 9; ++s) xv[s] = as[kc * 36 + itg * 9 + s];
#pragma unroll
            for (int s = 0; s < 9; ++s) {
                acc[0][s] += wr.x * xv[s];
                acc[1][s] += wr.y * xv[s];
                acc[2][s] += wr.z * xv[s];
                acc[3][s] += wr.w * xv[s];
            }
        }
        __syncthreads();
    }
#pragma unroll
    for (int r = 0; r < 4; ++r) {
        int o = og * 4 + r;
        float bb = bias[o];
#pragma unroll
        for (int s = 0; s < 9; ++s) {
            int gidx = (b * 256 + o) * 576 + i0 + itg * 9 + s;
            y[gidx] = acc[r][s] + bb + x[gidx];
        }
    }
}

// ---------------------------------------------------------------------------
// Kernel E: GroupNorm(16 groups), IN PLACE on d_out.
// ---------------------------------------------------------------------------
__global__ __launch_bounds__(256) void gn_k(float* __restrict__ y,
                                            const float* __restrict__ gw,
                                            const float* __restrict__ gb) {
    __shared__ double psum[4], psq[4];
    __shared__ float stat[2];
    int b = blockIdx.x >> 4, grp = blockIdx.x & 15;
    size_t base = ((size_t)b * 256 + grp * 16) * 576;
    int tid = threadIdx.x;
    int lane = tid & 63, wid = tid >> 6;

    float4 vals[9];
    double s = 0.0, s2 = 0.0;
#pragma unroll
    for (int k = 0; k < 9; ++k) {
        float4 v = *reinterpret_cast<const float4*>(&y[base + (size_t)(k * 256 + tid) * 4]);
        vals[k] = v;
        s += (double)v.x + (double)v.y + (double)v.z + (double)v.w;
        s2 += (double)v.x * v.x + (double)v.y * v.y + (double)v.z * v.z + (double)v.w * v.w;
    }
#pragma unroll
    for (int off = 32; off > 0; off >>= 1) {
        s += __shfl_down(s, off);
        s2 += __shfl_down(s2, off);
    }
    if (lane == 0) { psum[wid] = s; psq[wid] = s2; }
    __syncthreads();
    if (tid == 0) {
        double ts = psum[0] + psum[1] + psum[2] + psum[3];
        double tq = psq[0] + psq[1] + psq[2] + psq[3];
        double mean = ts * (1.0 / 9216.0);
        double var = tq * (1.0 / 9216.0) - mean * mean;
        stat[0] = (float)mean;
        stat[1] = (float)(1.0 / sqrt(var + 1e-5));
    }
    __syncthreads();
    float mf = stat[0], rstd = stat[1];
#pragma unroll
    for (int k = 0; k < 9; ++k) {
        int idx4 = k * 256 + tid;
        int ch = grp * 16 + idx4 / 144;
        float wv = gw[ch], bv = gb[ch];
        float4 v = vals[k];
        float4 r;
        r.x = (v.x - mf) * rstd * wv + bv;
        r.y = (v.y - mf) * rstd * wv + bv;
        r.z = (v.z - mf) * rstd * wv + bv;
        r.w = (v.w - mf) * rstd * wv + bv;
        *reinterpret_cast<float4*>(&y[base + (size_t)idx4 * 4]) = r;
    }
}

// ---------------------------------------------------------------------------
extern "C" void kernel_launch(void* const* d_in, const int* in_sizes, int n_in,
                              void* d_out, int out_size, void* d_ws, size_t ws_size,
                              hipStream_t stream) {
    const float* x     = (const float*)d_in[0];
    const float* qkv_w = (const float*)d_in[1];
    const float* qkv_b = (const float*)d_in[2];
    const float* rh_k  = (const float*)d_in[3];
    const float* rw_k  = (const float*)d_in[4];
    const float* rh_v  = (const float*)d_in[5];
    const float* rw_v  = (const float*)d_in[6];
    const float* fc_w  = (const float*)d_in[7];
    const float* fc_b  = (const float*)d_in[8];
    const float* gn_w  = (const float*)d_in[9];
    const float* gn_b  = (const float*)d_in[10];
    float* out = (float*)d_out;

    float* qkv = (float*)d_ws;            // 16*768*576 = 7,077,888 floats (27.0 MB)
    float* att = qkv + 7077888;           // 16*256*576 = 2,359,296 floats (9.0 MB)

    qkv_gemm_k<<<768, 256, 0, stream>>>(x, qkv_w, qkv_b, qkv);
    attn_k<<<256, 512, 0, stream>>>(qkv, rh_k, rw_k, rh_v, rw_v, att);
    fc_k<<<256, 256, 0, stream>>>(att, fc_w, fc_b, x, out);   // y -> d_out
    gn_k<<<256, 256, 0, stream>>>(out, gn_w, gn_b);           // in-place GN
}

// Round 11
// 541.832 us; speedup vs baseline: 1.4658x; 1.4658x over previous
//
#include <hip/hip_runtime.h>
#include <math.h>

// Problem constants
#define BB 16
#define CHN 256
#define TT 576
#define NHD 8
#define DHD 32
#define SCALE_F 0.17677669529663687f  // 1/sqrt(32)

// XOR chunk swizzle: element (row p, depth d) -> byte-conflict-free float offset
__device__ __forceinline__ int SW(int p, int d) {
    return ((((d >> 2) ^ (p & 7)) << 2) | (d & 3));
}

// ---------------------------------------------------------------------------
// Kernel A: QKV 1x1-conv GEMM.  out[b][o][i] = sum_c w[o][c]*x[b][c][i] + bias[o]
// Grid: 16 b * 16 i-tiles(36) * 3 o-chunks(256) = 768 blocks, 256 threads.
// ---------------------------------------------------------------------------
__global__ __launch_bounds__(256) void qkv_gemm_k(const float* __restrict__ x,
                                                  const float* __restrict__ w,
                                                  const float* __restrict__ bias,
                                                  float* __restrict__ out) {
    __shared__ float ws[32 * 260];   // [kc][oo], stride 260
    __shared__ float xs[32 * 36];    // [kc][ii]
    int orig = blockIdx.x;
    int wg = (orig & 7) * 96 + (orig >> 3);      // XCD-chunked swizzle
    int b = wg / 48;
    int rem = wg % 48;
    int it = rem / 3, oh = rem % 3;
    int o0 = oh * 256, i0 = it * 36;
    int tid = threadIdx.x;
    int og = tid >> 2, itg = tid & 3;            // thread owns 4 o x 9 i

    float acc[4][9];
#pragma unroll
    for (int r = 0; r < 4; ++r)
#pragma unroll
        for (int s = 0; s < 9; ++s) acc[r][s] = 0.f;

    for (int kt = 0; kt < 8; ++kt) {
        for (int idx4 = tid; idx4 < 2048; idx4 += 256) {
            int oo = idx4 >> 3, kc4 = (idx4 & 7) * 4;
            const float4 v = *reinterpret_cast<const float4*>(&w[(o0 + oo) * 256 + kt * 32 + kc4]);
            ws[(kc4 + 0) * 260 + oo] = v.x;
            ws[(kc4 + 1) * 260 + oo] = v.y;
            ws[(kc4 + 2) * 260 + oo] = v.z;
            ws[(kc4 + 3) * 260 + oo] = v.w;
        }
        for (int idx4 = tid; idx4 < 288; idx4 += 256) {
            int kc = idx4 / 9, ii4 = idx4 % 9;
            const float4 v = *reinterpret_cast<const float4*>(&x[(b * 256 + kt * 32 + kc) * 576 + i0 + ii4 * 4]);
            *reinterpret_cast<float4*>(&xs[kc * 36 + ii4 * 4]) = v;
        }
        __syncthreads();
#pragma unroll 8
        for (int kc = 0; kc < 32; ++kc) {
            float4 wr = *reinterpret_cast<const float4*>(&ws[kc * 260 + og * 4]);
            float xv[9];
#pragma unroll
            for (int s = 0; s < 9; ++s) xv[s] = xs[kc * 36 + itg * 9 + s];
#pragma unroll
            for (int s = 0; s < 9; ++s) {
                acc[0][s] += wr.x * xv[s];
                acc[1][s] += wr.y * xv[s];
                acc[2][s] += wr.z * xv[s];
                acc[3][s] += wr.w * xv[s];
            }
        }
        __syncthreads();
    }
#pragma unroll
    for (int r = 0; r < 4; ++r) {
        int o = o0 + og * 4 + r;
        float bb = bias[o];
#pragma unroll
        for (int s = 0; s < 9; ++s)
            out[(b * 768 + o) * 576 + i0 + itg * 9 + s] = acc[r][s] + bb;
    }
}

// ---------------------------------------------------------------------------
// Kernel C: fused attention — 18-row tiles, 512 blocks x 256 threads, 71 KB LDS
// => 2 blocks/CU (8 waves/CU). 256-thr blocks proved spill-free at VGPR=160 (R3).
// V and rel-pos tables are read from GLOBAL (L2-resident) — no LDS staging.
// Per 32-lane head-group: phase1 = {dh(2) x ig1(2)x9i x jg1(8)x3c}, half-dot
// + shfl_xor(16); phase2 = {dg(8)x4d x ig2(2)x9i x ch(2) c-half}, shfl_xor(1).
// ---------------------------------------------------------------------------
__global__ __launch_bounds__(256) void attn_k(const float* __restrict__ qkv,
                                              const float* __restrict__ rh_k,
                                              const float* __restrict__ rw_k,
                                              const float* __restrict__ rh_v,
                                              const float* __restrict__ rw_v,
                                              float* __restrict__ att_out) {
    __shared__ float qs[8192];    // q window [n][iw<32][d=32] swizzled (rows [i0,i0+32))
    __shared__ float kvs[6144];   // K tile [n][c=24][d=32] swizzled
    __shared__ float ats[3456];   // logits/probs [n][i=18][c=24]; end: colsum

    int orig = blockIdx.x;
    int wg = (orig & 7) * 64 + (orig >> 3);      // XCD-chunked swizzle (512 % 8 == 0)
    int b = wg >> 5, it = wg & 31;
    int i0 = it * 18;
    int tid = threadIdx.x;
    const float* qb = qkv + (size_t)b * 768 * 576;
    const float* kplane = qb + 256 * 576;
    const float* vplane = qb + 512 * 576;

    // thread ids (g = lane within 32-thread head-group)
    int n1 = tid >> 5;
    int g = tid & 31;
    int dh = g >> 4;                               // phase1 d-half
    int ig1 = (g >> 3) & 1, jg1 = g & 7;           // phase1: 2x9 i, 8x3 c
    int dg = g >> 2, ig2 = (g >> 1) & 1, ch = g & 1; // phase2: 8x4 d, 2x9 i, 2 c-halves
    int d0 = dg * 4, ib = ig2 * 9;

    // ---- load q window rows [i0, i0+32) (clipped) transposed+swizzled ----
#pragma unroll
    for (int k = 0; k < 8; ++k) {
        int idx4 = tid + k * 256;
        int o = idx4 >> 3, iw4 = (idx4 & 7) * 4;
        int n = o >> 5, d = o & 31;
        int gi = i0 + iw4;
        float4 v;
        if (gi + 3 < 576) {
            v = *reinterpret_cast<const float4*>(&qb[o * 576 + gi]);
        } else {
            v.x = (gi + 0 < 576) ? qb[o * 576 + gi + 0] : 0.f;
            v.y = (gi + 1 < 576) ? qb[o * 576 + gi + 1] : 0.f;
            v.z = (gi + 2 < 576) ? qb[o * 576 + gi + 2] : 0.f;
            v.w = (gi + 3 < 576) ? qb[o * 576 + gi + 3] : 0.f;
        }
        qs[n * 1024 + (iw4 + 0) * 32 + SW(iw4 + 0, d)] = v.x;
        qs[n * 1024 + (iw4 + 1) * 32 + SW(iw4 + 1, d)] = v.y;
        qs[n * 1024 + (iw4 + 2) * 32 + SW(iw4 + 2, d)] = v.z;
        qs[n * 1024 + (iw4 + 3) * 32 + SW(iw4 + 3, d)] = v.w;
    }
    __syncthreads();

    // ---- bd HALF-dots into regs: bdreg[r][s] = dot16(q[:,isrc], (rh_k+rw_k)[j-1]) ----
    // tables read from global (L2/L3-hot: 96 KB shared by all blocks)
    float bdreg[9][3];
#pragma unroll
    for (int r = 0; r < 9; ++r) {
        int i_loc = ig1 * 9 + r;
        int f0 = 576 + 47 * (i0 + i_loc);
#pragma unroll
        for (int s = 0; s < 3; ++s) {
            int c = jg1 * 3 + s;
            int f = f0 + c;
            int j = f % 48;
            float val = 0.f;
            if (j > 0) {
                int isl = f / 48 - i0;   // proven in [0,30) subset of [0,32)
                int bq = n1 * 1024 + isl * 32;
                int swz = isl & 7;
                int toff = (j - 1) * 256 + n1 * 32 + dh * 16;
#pragma unroll
                for (int dq = 0; dq < 4; ++dq) {
                    int dqq = dh * 4 + dq;
                    float4 qv = *reinterpret_cast<const float4*>(&qs[bq + ((dqq ^ swz) << 2)]);
                    float4 r1 = *reinterpret_cast<const float4*>(&rh_k[toff + dq * 4]);
                    float4 r2 = *reinterpret_cast<const float4*>(&rw_k[toff + dq * 4]);
                    val += qv.x * (r1.x + r2.x) + qv.y * (r1.y + r2.y) +
                           qv.z * (r1.z + r2.z) + qv.w * (r1.w + r2.w);
                }
            }
            bdreg[r][s] = val;
        }
    }

    // persistent state
    float cs[2][8];      // colsum (432 pairs / 256 threads -> <=2 slots)
#pragma unroll
    for (int k = 0; k < 2; ++k)
#pragma unroll
        for (int nn = 0; nn < 8; ++nn) cs[k][nn] = 0.f;
    float acc[4][9];
#pragma unroll
    for (int r = 0; r < 4; ++r)
#pragma unroll
        for (int s = 0; s < 9; ++s) acc[r][s] = 0.f;

    for (int tt = 0; tt < 24; ++tt) {
        // ---- issue V loads for this tile early (global, row-contiguous) ----
        float4 vr[4][3];
#pragma unroll
        for (int r = 0; r < 4; ++r) {
            const float* vrow = vplane + (n1 * 32 + d0 + r) * 576 + tt * 24 + ch * 12;
#pragma unroll
            for (int jj = 0; jj < 3; ++jj)
                vr[r][jj] = *reinterpret_cast<const float4*>(&vrow[jj * 4]);
        }
        // ---- stage K tile global -> LDS [n][c][d] swizzled ----
#pragma unroll
        for (int k = 0; k < 6; ++k) {
            int idx4 = tid + k * 256;
            int o = idx4 / 6, c4 = (idx4 % 6) * 4;
            int n = o >> 5, d = o & 31;
            float4 kv = *reinterpret_cast<const float4*>(&kplane[o * 576 + tt * 24 + c4]);
            int base = n * 768;
            kvs[base + (c4 + 0) * 32 + SW(c4 + 0, d)] = kv.x;
            kvs[base + (c4 + 1) * 32 + SW(c4 + 1, d)] = kv.y;
            kvs[base + (c4 + 2) * 32 + SW(c4 + 2, d)] = kv.z;
            kvs[base + (c4 + 3) * 32 + SW(c4 + 3, d)] = kv.w;
        }
        __syncthreads();   // barB: K ready; prev phase2's ats reads done

        // ---- phase 1: half-logits, shfl_xor(16) combine, dh==0 writes ----
        {
            float a[9][3];
#pragma unroll
            for (int r = 0; r < 9; ++r)
#pragma unroll
                for (int s = 0; s < 3; ++s) a[r][s] = bdreg[r][s];
#pragma unroll
            for (int dq = 0; dq < 4; ++dq) {
                int dqq = dh * 4 + dq;
                float4 qv[9], kv[3];
#pragma unroll
                for (int r = 0; r < 9; ++r) {
                    int iw = ig1 * 9 + r;
                    qv[r] = *reinterpret_cast<const float4*>(&qs[n1 * 1024 + iw * 32 + ((dqq ^ (iw & 7)) << 2)]);
                }
#pragma unroll
                for (int s = 0; s < 3; ++s) {
                    int c = jg1 * 3 + s;
                    kv[s] = *reinterpret_cast<const float4*>(&kvs[n1 * 768 + c * 32 + ((dqq ^ (c & 7)) << 2)]);
                }
#pragma unroll
                for (int r = 0; r < 9; ++r)
#pragma unroll
                    for (int s = 0; s < 3; ++s)
                        a[r][s] += qv[r].x * kv[s].x + qv[r].y * kv[s].y +
                                   qv[r].z * kv[s].z + qv[r].w * kv[s].w;
            }
#pragma unroll
            for (int r = 0; r < 9; ++r)
#pragma unroll
                for (int s = 0; s < 3; ++s)
                    a[r][s] += __shfl_xor(a[r][s], 16);   // combine d-halves
            if (dh == 0) {
#pragma unroll
                for (int r = 0; r < 9; ++r)
#pragma unroll
                    for (int s = 0; s < 3; ++s)
                        ats[n1 * 432 + (ig1 * 9 + r) * 24 + jg1 * 3 + s] = a[r][s] * SCALE_F;
            }
        }
        __syncthreads();   // barC: logits ready

        // ---- softmax over 8 heads per (i,c); colsum in regs ----
        {
            int p = tid;
            float xv[8];
#pragma unroll
            for (int nn = 0; nn < 8; ++nn) xv[nn] = ats[nn * 432 + p];
            float m = xv[0];
#pragma unroll
            for (int nn = 1; nn < 8; ++nn) m = fmaxf(m, xv[nn]);
            float ssum = 0.f;
#pragma unroll
            for (int nn = 0; nn < 8; ++nn) { xv[nn] = __expf(xv[nn] - m); ssum += xv[nn]; }
            float inv = 1.0f / ssum;
#pragma unroll
            for (int nn = 0; nn < 8; ++nn) {
                float aa = xv[nn] * inv;
                ats[nn * 432 + p] = aa;
                cs[0][nn] += aa;
            }
            if (tid < 176) {
                int p2 = 256 + tid;
                float yv[8];
#pragma unroll
                for (int nn = 0; nn < 8; ++nn) yv[nn] = ats[nn * 432 + p2];
                float m2 = yv[0];
#pragma unroll
                for (int nn = 1; nn < 8; ++nn) m2 = fmaxf(m2, yv[nn]);
                float ss2 = 0.f;
#pragma unroll
                for (int nn = 0; nn < 8; ++nn) { yv[nn] = __expf(yv[nn] - m2); ss2 += yv[nn]; }
                float inv2 = 1.0f / ss2;
#pragma unroll
                for (int nn = 0; nn < 8; ++nn) {
                    float aa = yv[nn] * inv2;
                    ats[nn * 432 + p2] = aa;
                    cs[1][nn] += aa;
                }
            }
        }
        __syncthreads();   // barD: probs ready

        // ---- phase 2: acc += attn @ V (probs LDS, V in regs from global) ----
#pragma unroll
        for (int s = 0; s < 9; ++s) {
            const float* abase = &ats[n1 * 432 + (ib + s) * 24 + ch * 12];
            float4 pv0 = *reinterpret_cast<const float4*>(&abase[0]);
            float4 pv1 = *reinterpret_cast<const float4*>(&abase[4]);
            float4 pv2 = *reinterpret_cast<const float4*>(&abase[8]);
#pragma unroll
            for (int r = 0; r < 4; ++r) {
                acc[r][s] += vr[r][0].x * pv0.x + vr[r][0].y * pv0.y +
                             vr[r][0].z * pv0.z + vr[r][0].w * pv0.w +
                             vr[r][1].x * pv1.x + vr[r][1].y * pv1.y +
                             vr[r][1].z * pv1.z + vr[r][1].w * pv1.w +
                             vr[r][2].x * pv2.x + vr[r][2].y * pv2.y +
                             vr[r][2].z * pv2.z + vr[r][2].w * pv2.w;
            }
        }
    }
    __syncthreads();   // last phase2 ats reads done

    // ---- combine c-halves of acc (lane^1 partner) ----
#pragma unroll
    for (int r = 0; r < 4; ++r)
#pragma unroll
        for (int s = 0; s < 9; ++s)
            acc[r][s] += __shfl_xor(acc[r][s], 1);

    // ---- colsum -> ats ----
    {
        int p = tid;
#pragma unroll
        for (int nn = 0; nn < 8; ++nn) ats[nn * 432 + p] = cs[0][nn];
        if (tid < 176) {
            int p2 = 256 + tid;
#pragma unroll
            for (int nn = 0; nn < 8; ++nn) ats[nn * 432 + p2] = cs[1][nn];
        }
    }
    __syncthreads();

    // ---- positional-value epilogue + write; tables from global (L2-hot).
    //      STATIC unroll over s; wave-uniform-per-lane guard only (rule #20).
#pragma unroll
    for (int s = 0; s < 9; ++s) {
        bool mine = (s < 5) ? (ch == 0) : (ch == 1);
        if (mine) {
            int i_loc = ib + s;
            int f0 = 576 + 47 * (i0 + i_loc);
            float a0 = acc[0][s], a1 = acc[1][s], a2 = acc[2][s], a3 = acc[3][s];
#pragma unroll 4
            for (int c = 0; c < 24; ++c) {
                int f = f0 + c;
                int j = f % 48;
                if (j > 0) {
                    float wv = ats[n1 * 432 + i_loc * 24 + c];
                    int toff = (j - 1) * 256 + n1 * 32 + d0;
                    float4 r1 = *reinterpret_cast<const float4*>(&rh_v[toff]);
                    float4 r2 = *reinterpret_cast<const float4*>(&rw_v[toff]);
                    a0 += wv * (r1.x + r2.x);
                    a1 += wv * (r1.y + r2.y);
                    a2 += wv * (r1.z + r2.z);
                    a3 += wv * (r1.w + r2.w);
                }
            }
            size_t ob = ((size_t)b * 256 + n1 * 32 + d0) * 576 + i0 + i_loc;
            att_out[ob] = a0;
            att_out[ob + 576] = a1;
            att_out[ob + 1152] = a2;
            att_out[ob + 1728] = a3;
        }
    }
}

// ---------------------------------------------------------------------------
// Kernel D: FC 1x1-conv GEMM + bias + residual. Writes into d_out.
// ---------------------------------------------------------------------------
__global__ __launch_bounds__(256) void fc_k(const float* __restrict__ att,
                                            const float* __restrict__ w,
                                            const float* __restrict__ bias,
                                            const float* __restrict__ x,
                                            float* __restrict__ y) {
    __shared__ float ws[32 * 260];
    __shared__ float as[32 * 36];
    int orig = blockIdx.x;
    int wg = (orig & 7) * 32 + (orig >> 3);
    int b = wg >> 4, it = wg & 15;
    int i0 = it * 36;
    int tid = threadIdx.x;
    int og = tid >> 2, itg = tid & 3;

    float acc[4][9];
#pragma unroll
    for (int r = 0; r < 4; ++r)
#pragma unroll
        for (int s = 0; s < 9; ++s) acc[r][s] = 0.f;

    for (int kt = 0; kt < 8; ++kt) {
        for (int idx4 = tid; idx4 < 2048; idx4 += 256) {
            int oo = idx4 >> 3, kc4 = (idx4 & 7) * 4;
            const float4 v = *reinterpret_cast<const float4*>(&w[oo * 256 + kt * 32 + kc4]);
            ws[(kc4 + 0) * 260 + oo] = v.x;
            ws[(kc4 + 1) * 260 + oo] = v.y;
            ws[(kc4 + 2) * 260 + oo] = v.z;
            ws[(kc4 + 3) * 260 + oo] = v.w;
        }
        for (int idx4 = tid; idx4 < 288; idx4 += 256) {
            int kc = idx4 / 9, ii4 = idx4 % 9;
            const float4 v = *reinterpret_cast<const float4*>(&att[(b * 256 + kt * 32 + kc) * 576 + i0 + ii4 * 4]);
            *reinterpret_cast<float4*>(&as[kc * 36 + ii4 * 4]) = v;
        }
        __syncthreads();
#pragma unroll 8
        for (int kc = 0; kc < 32; ++kc) {
            float4 wr = *reinterpret_cast<const float4*>(&ws[kc * 260 + og * 4]);
            float xv[9];
#pragma unroll
            for (int s = 0; s < 9; ++s) xv[s] = as[kc * 36 + itg * 9 + s];
#pragma unroll
            for (int s = 0; s < 9; ++s) {
                acc[0][s] += wr.x * xv[s];
                acc[1][s] += wr.y * xv[s];
                acc[2][s] += wr.z * xv[s];
                acc[3][s] += wr.w * xv[s];
            }
        }
        __syncthreads();
    }
#pragma unroll
    for (int r = 0; r < 4; ++r) {
        int o = og * 4 + r;
        float bb = bias[o];
#pragma unroll
        for (int s = 0; s < 9; ++s) {
            int gidx = (b * 256 + o) * 576 + i0 + itg * 9 + s;
            y[gidx] = acc[r][s] + bb + x[gidx];
        }
    }
}

// ---------------------------------------------------------------------------
// Kernel E: GroupNorm(16 groups), IN PLACE on d_out.
// ---------------------------------------------------------------------------
__global__ __launch_bounds__(256) void gn_k(float* __restrict__ y,
                                            const float* __restrict__ gw,
                                            const float* __restrict__ gb) {
    __shared__ double psum[4], psq[4];
    __shared__ float stat[2];
    int b = blockIdx.x >> 4, grp = blockIdx.x & 15;
    size_t base = ((size_t)b * 256 + grp * 16) * 576;
    int tid = threadIdx.x;
    int lane = tid & 63, wid = tid >> 6;

    float4 vals[9];
    double s = 0.0, s2 = 0.0;
#pragma unroll
    for (int k = 0; k < 9; ++k) {
        float4 v = *reinterpret_cast<const float4*>(&y[base + (size_t)(k * 256 + tid) * 4]);
        vals[k] = v;
        s += (double)v.x + (double)v.y + (double)v.z + (double)v.w;
        s2 += (double)v.x * v.x + (double)v.y * v.y + (double)v.z * v.z + (double)v.w * v.w;
    }
#pragma unroll
    for (int off = 32; off > 0; off >>= 1) {
        s += __shfl_down(s, off);
        s2 += __shfl_down(s2, off);
    }
    if (lane == 0) { psum[wid] = s; psq[wid] = s2; }
    __syncthreads();
    if (tid == 0) {
        double ts = psum[0] + psum[1] + psum[2] + psum[3];
        double tq = psq[0] + psq[1] + psq[2] + psq[3];
        double mean = ts * (1.0 / 9216.0);
        double var = tq * (1.0 / 9216.0) - mean * mean;
        stat[0] = (float)mean;
        stat[1] = (float)(1.0 / sqrt(var + 1e-5));
    }
    __syncthreads();
    float mf = stat[0], rstd = stat[1];
#pragma unroll
    for (int k = 0; k < 9; ++k) {
        int idx4 = k * 256 + tid;
        int ch = grp * 16 + idx4 / 144;
        float wv = gw[ch], bv = gb[ch];
        float4 v = vals[k];
        float4 r;
        r.x = (v.x - mf) * rstd * wv + bv;
        r.y = (v.y - mf) * rstd * wv + bv;
        r.z = (v.z - mf) * rstd * wv + bv;
        r.w = (v.w - mf) * rstd * wv + bv;
        *reinterpret_cast<float4*>(&y[base + (size_t)idx4 * 4]) = r;
    }
}

// ---------------------------------------------------------------------------
extern "C" void kernel_launch(void* const* d_in, const int* in_sizes, int n_in,
                              void* d_out, int out_size, void* d_ws, size_t ws_size,
                              hipStream_t stream) {
    const float* x     = (const float*)d_in[0];
    const float* qkv_w = (const float*)d_in[1];
    const float* qkv_b = (const float*)d_in[2];
    const float* rh_k  = (const float*)d_in[3];
    const float* rw_k  = (const float*)d_in[4];
    const float* rh_v  = (const float*)d_in[5];
    const float* rw_v  = (const float*)d_in[6];
    const float* fc_w  = (const float*)d_in[7];
    const float* fc_b  = (const float*)d_in[8];
    const float* gn_w  = (const float*)d_in[9];
    const float* gn_b  = (const float*)d_in[10];
    float* out = (float*)d_out;

    float* qkv = (float*)d_ws;            // 16*768*576 = 7,077,888 floats (27.0 MB)
    float* att = qkv + 7077888;           // 16*256*576 = 2,359,296 floats (9.0 MB)

    qkv_gemm_k<<<768, 256, 0, stream>>>(x, qkv_w, qkv_b, qkv);
    attn_k<<<512, 256, 0, stream>>>(qkv, rh_k, rw_k, rh_v, rw_v, att);
    fc_k<<<256, 256, 0, stream>>>(att, fc_w, fc_b, x, out);   // y -> d_out
    gn_k<<<256, 256, 0, stream>>>(out, gn_w, gn_b);           // in-place GN
}